// Round 23
// baseline (194.381 us; speedup 1.0000x reference)
//
#include <hip/hip_runtime.h>
#include <hip/hip_bf16.h>

typedef unsigned short u16;
typedef _Float16 f16;
typedef f16 f16x8 __attribute__((ext_vector_type(8)));
typedef float f32x4 __attribute__((ext_vector_type(4)));

__device__ __forceinline__ float b2f(u16 u) {
  unsigned v = (unsigned)u << 16; float f; __builtin_memcpy(&f, &v, 4); return f;
}
__device__ __forceinline__ u16 f2b(float f) {
  return __builtin_bit_cast(u16, __float2bfloat16(f));
}
__device__ __forceinline__ float h2f(u16 u) {
  return (float)__builtin_bit_cast(f16, u);
}
__device__ __forceinline__ u16 f2h(float f) {
  return __builtin_bit_cast(u16, (f16)f);
}
__device__ __forceinline__ void gload16(const void* g, void* l) {
  __builtin_amdgcn_global_load_lds((__attribute__((address_space(1))) void*)(const_cast<void*>(g)),
                                   (__attribute__((address_space(3))) void*)l, 16, 0, 0);
}
__device__ __forceinline__ f32x4 mfma16(int4 a, int4 b, f32x4 c) {
  return __builtin_amdgcn_mfma_f32_16x16x32_f16(__builtin_bit_cast(f16x8, a),
                                                __builtin_bit_cast(f16x8, b), c, 0, 0, 0);
}
union PK { int4 i; u16 u[8]; };

// Self dtype detect: sample 1024 even u16s of x; f32 buffer -> ~44% have exp-field>=0x90, bf16 -> 0.
__device__ __forceinline__ int detect_isf(const u16* x, int tid, int nthr) {
  __shared__ int dcnt;
  if (tid == 0) dcnt = 0;
  __syncthreads();
  int c = 0;
  for (int i = tid; i < 1024; i += nthr) {
    u16 u = x[i * 2];
    if (((u >> 7) & 0xFF) >= 0x90) ++c;
  }
  if (c) atomicAdd(&dcnt, c);
  __syncthreads();
  return dcnt > 16;
}

// xnt padded frag-major layout: row (b*130 + h+1), 2080 chunks of 16B; chunk = g*130 + (w+1);
// chunk holds xn[c = g*8 .. g*8+8) at column w. Pad rows (h=-1,128) and pad cols (w=-1,128) zero.
#define XROW 33280

// ---------------- K0+K1 merged: blocks 0..26 build weff (frag-major); blocks 27..282 LayerNorm
// rows; blocks 283..286 zero pad rows; LN block 27 also zeroes attnb.
__global__ __launch_bounds__(256) void k_lnweff(
    const void* __restrict__ xr, const void* __restrict__ gr, const void* __restrict__ br_,
    const void* __restrict__ w1q, const void* __restrict__ w2q,
    const void* __restrict__ w1k, const void* __restrict__ w2k,
    const void* __restrict__ w1v, const void* __restrict__ w2v,
    u16* __restrict__ weff, u16* __restrict__ xnt, float* __restrict__ attnb) {
  __shared__ __align__(16) char smem[99328];   // overlay: weff path 64KB; LN path 97KB
  int tid = threadIdx.x;
  int bi = blockIdx.x;

  if (bi < 27) {
    u16* sA = (u16*)smem;                      // w2t [c][m ^ 8*(c&15)]
    u16* sB = (u16*)(smem + 32768);            // w1t [ci][m ^ 8*(ci&15)]
    int isf = detect_isf((const u16*)xr, tid, 256);
    int blk = bi;                              // tap*3 + br
    int tap = blk / 3, br = blk - tap * 3;
    const void* w1 = br == 0 ? w1q : (br == 1 ? w1k : w1v);
    const void* w2 = br == 0 ? w2q : (br == 1 ? w2k : w2v);
    if (isf) {
      const float* w2f = (const float*)w2;
      const float* w1f = (const float*)w1;
#pragma unroll 4
      for (int i = 0; i < 64; ++i) {
        int e = i * 256 + tid;
        int c = e >> 7, m = e & 127;
        sA[c * 128 + (m ^ ((c & 15) << 3))] = f2h(w2f[e * 9 + tap]);
        int ci = e & 127;
        sB[ci * 128 + ((e >> 7) ^ ((ci & 15) << 3))] = f2h(w1f[e]);
      }
    } else {
      const u16* w2u = (const u16*)w2;
      const u16* w1u = (const u16*)w1;
#pragma unroll 4
      for (int i = 0; i < 64; ++i) {
        int e = i * 256 + tid;
        int c = e >> 7, m = e & 127;
        sA[c * 128 + (m ^ ((c & 15) << 3))] = f2h(b2f(w2u[e * 9 + tap]));
        int ci = e & 127;
        sB[ci * 128 + ((e >> 7) ^ ((ci & 15) << 3))] = f2h(b2f(w1u[e]));
      }
    }
    __syncthreads();
    int lane = tid & 63, wv = tid >> 6;
    int m0w = (wv >> 1) * 64, n0w = (wv & 1) * 64;   // c-range, ci-range
    f32x4 acc[4][4] = {};
#pragma unroll
    for (int k0 = 0; k0 < 4; ++k0) {
      int mrow = k0 * 32 + (lane >> 4) * 8;
      int4 a4[4], b4[4];
#pragma unroll
      for (int mi = 0; mi < 4; ++mi) {
        int c = m0w + mi * 16 + (lane & 15);
        a4[mi] = *(const int4*)&sA[c * 128 + (mrow ^ ((c & 15) << 3))];
      }
#pragma unroll
      for (int ni = 0; ni < 4; ++ni) {
        int ci = n0w + ni * 16 + (lane & 15);
        b4[ni] = *(const int4*)&sB[ci * 128 + (mrow ^ ((ci & 15) << 3))];
      }
#pragma unroll
      for (int mi = 0; mi < 4; ++mi)
#pragma unroll
        for (int ni = 0; ni < 4; ++ni)
          acc[mi][ni] = mfma16(a4[mi], b4[ni], acc[mi][ni]);
    }
    __syncthreads();
#pragma unroll
    for (int mi = 0; mi < 4; ++mi)
#pragma unroll
      for (int ni = 0; ni < 4; ++ni) {
#pragma unroll
        for (int r = 0; r < 4; ++r) {
          int c = m0w + mi * 16 + (lane >> 4) * 4 + r;
          int ci = n0w + ni * 16 + (lane & 15);
          sA[c * 128 + ci] = f2h(acc[mi][ni][r]);    // LDS linear [c][ci]
        }
      }
    __syncthreads();
    int4* dst = (int4*)((char*)weff + (size_t)blk * 32768);
#pragma unroll
    for (int i = 0; i < 8; ++i) {
      int gidx = i * 256 + tid;
      int k0 = gidx >> 9;
      int ch = gidx & 511;
      int mt = ch >> 6, l = ch & 63;
      int c = mt * 16 + (l & 15);
      int g = k0 * 4 + (l >> 4);
      dst[gidx] = *(const int4*)((const char*)sA + c * 256 + g * 16);
    }
    return;
  }

  int li = bi - 27;                            // 0..259
  if (li >= 256) {                             // pad-row zeroing blocks
    int pid = li - 256;
    int b = pid >> 1, row = (pid & 1) ? 129 : 0;
    char* rbase = (char*)xnt + (size_t)(b * 130 + row) * XROW;
    int4 z = make_int4(0, 0, 0, 0);
    for (int i = 0; i < 9; ++i) {
      int idx = i * 256 + tid;
      if (idx < 2080) *(int4*)(rbase + idx * 16) = z;
    }
    return;
  }
  if (li == 0) {
    for (int i = tid; i < 4096; i += 256) attnb[i] = 0.f;
  }
  float* sx = (float*)smem;                    // 64KB raw f32 x, [c][chunk], phys = logical^(c&31)
  u16* sn = (u16*)(smem + 65536);              // 32KB f16 xn, [w][chunk g^(w&15)]
  float* sg = (float*)(smem + 98304);
  float* sb = (float*)(smem + 98816);
  int b = li >> 7, h = li & 127;
  int isf = detect_isf((const u16*)xr, tid, 256);
  if (tid < 128) {
    sg[tid] = isf ? ((const float*)gr)[tid] : b2f(((const u16*)gr)[tid]);
    sb[tid] = isf ? ((const float*)br_)[tid] : b2f(((const u16*)br_)[tid]);
  }
  if (isf) {
#pragma unroll
    for (int it = 0; it < 16; ++it) {
      int d = it * 4096 + tid * 16;
      int c = d >> 9;
      int p = (d >> 4) & 31;
      int sc = p ^ (c & 31);
      const char* src = (const char*)xr + (size_t)(b * 128 + c) * 65536 + (size_t)h * 512 + (sc << 4);
      gload16(src, (char*)sx + d);
    }
  } else {
    int c = tid >> 1, half = tid & 1;
    const u16* xu = (const u16*)xr + ((size_t)(b * 128 + c) * 128 + h) * 128 + half * 64;
    for (int i = 0; i < 16; ++i) {
      int phys = (half * 16 + i) ^ (c & 31);
      float* dst = sx + c * 128 + phys * 4;
#pragma unroll
      for (int j = 0; j < 4; ++j) dst[j] = b2f(xu[i * 4 + j]);
    }
  }
  __syncthreads();
  int c = tid >> 1, half = tid & 1;
  float sum = 0.f, sq = 0.f;
#pragma unroll
  for (int i = 0; i < 16; ++i) {
    int phys = (half * 16 + i) ^ (c & 31);
    const float* v = sx + c * 128 + phys * 4;
#pragma unroll
    for (int j = 0; j < 4; ++j) { float f = v[j]; sum += f; sq += f * f; }
  }
  sum += __shfl_xor(sum, 1);
  sq  += __shfl_xor(sq, 1);
  float mu = sum * 0.0078125f;
  float var = sq * 0.0078125f - mu * mu;
  float rs = rsqrtf(var + 1e-5f);
  int cg = c >> 3, cl = c & 7;
#pragma unroll
  for (int i = 0; i < 16; ++i) {
    int logical = half * 16 + i;
    int phys = logical ^ (c & 31);
    const float* v = sx + c * 128 + phys * 4;
#pragma unroll
    for (int j = 0; j < 4; ++j) {
      int w = logical * 4 + j;
      sn[w * 128 + (((cg ^ (w & 15)) << 3) | cl)] = f2h((v[j] - mu) * rs * sg[w] + sb[w]);
    }
  }
  __syncthreads();
  char* obase = (char*)xnt + (size_t)(b * 130 + h + 1) * XROW;
#pragma unroll
  for (int i = 0; i < 8; ++i) {
    int idx = i * 256 + tid;
    int g = idx >> 7, w = idx & 127;
    int phys = g ^ (w & 15);
    *(int4*)(obase + (g * 130 + w + 1) * 16) = *(const int4*)((const char*)sn + w * 256 + (phys << 4));
  }
  if (tid < 32) {
    int g = tid >> 1, side = tid & 1;
    *(int4*)(obase + (g * 130 + (side ? 129 : 0)) * 16) = make_int4(0, 0, 0, 0);
  }
}

// ---------------- K2: Q,K,V eff-3x3 conv, CO-QUARTER split (block = b,h,coq: co 32 x w 128).
// 1024 blocks -> 4 blocks/CU (16 waves/CU TLP hides stage drains). 8KB/tile staged, 2x8KB dbuf,
// LDS 24KB. 27 steps x 16 MFMA/wave, plain __syncthreads. bc loaded per tap (no dbuf, L2-hot).
// Fused per-head Gram (2 heads/block, wave-pair split) -> f32 atomics.
#define STAGE_T(T, BUF) do { \
    const char* base_ = (const char*)weff + (size_t)(T) * 32768 + (size_t)coq * 2048; \
    char* dst_ = wq + (BUF) * 8192; \
    _Pragma("unroll") \
    for (int i_ = 0; i_ < 2; ++i_) \
      gload16(base_ + (size_t)(i_ * 2 + (tid >> 7)) * 8192 + (tid & 127) * 16, \
              dst_ + i_ * 4096 + tid * 16); \
  } while (0)

#define BC_LOAD(DST, T6) do { \
    int dy_ = (T6) / 3, dx_ = (T6) % 3; \
    const char* rb_ = (const char*)xnt + (size_t)(b * 130 + h + dy_) * XROW; \
    _Pragma("unroll") \
    for (int kk = 0; kk < 4; ++kk) \
      _Pragma("unroll") \
      for (int ni = 0; ni < 2; ++ni) { \
        int wp1 = n0l + ni * 16 + (lane & 15) + dx_;   /* w+1, always 0..129 */ \
        int chunk = (kk * 4 + (lane >> 4)) * 130 + wp1; \
        DST[kk][ni] = *(const int4*)(rb_ + chunk * 16); \
      } \
  } while (0)

#define QFULL(ACC, QB) do { \
    _Pragma("unroll") \
    for (int k0 = 0; k0 < 4; ++k0) { \
      int4 af[2]; \
      _Pragma("unroll") \
      for (int mi = 0; mi < 2; ++mi) \
        af[mi] = *(const int4*)((QB) + (k0 >> 1) * 4096 + (k0 & 1) * 2048 + mi * 1024 + lane * 16); \
      _Pragma("unroll") \
      for (int mi = 0; mi < 2; ++mi) { \
        ACC[mi][0] = mfma16(af[mi], bcA[k0][0], ACC[mi][0]); \
        ACC[mi][1] = mfma16(af[mi], bcA[k0][1], ACC[mi][1]); \
      } \
    } \
  } while (0)

__global__ __launch_bounds__(256, 4) void k_conv(const u16* __restrict__ xnt,
    const u16* __restrict__ weff, u16* __restrict__ Vc, float* __restrict__ attnb) {
  __shared__ __align__(16) char wq[24576];      // 2x8KB dbuf; epilogue scrQ/K/V 24KB
  int tid = threadIdx.x, lane = tid & 63, wv = tid >> 6;
  int bi = blockIdx.x;
  int coq = bi & 3, h = (bi >> 2) & 127, b = bi >> 9;
  int n0l = wv * 32;                            // wave's w range (32 of 128)

  int4 bcA[4][2];
  BC_LOAD(bcA, 0);
  STAGE_T(0, 0);
  __syncthreads();

  f32x4 aq[2][2] = {}, ak[2][2] = {}, av[2][2] = {};

  for (int t = 0; t < 27; ++t) {                // t = tap*3 + br
    int br = t % 3, tgrp = t / 3;
    if (t + 1 < 27) STAGE_T(t + 1, (t + 1) & 1);     // prefetch next co-quarter tile
    if (br == 0 && tgrp > 0) BC_LOAD(bcA, tgrp);     // fresh tap fragments (L2-hot, TLP-hidden)
    const char* qb = wq + (t & 1) * 8192;
    if (br == 0)      QFULL(aq, qb);
    else if (br == 1) QFULL(ak, qb);
    else              QFULL(av, qb);
    __syncthreads();                            // drains prefetch; protects buffer reuse
  }
  // ---- epilogue: Q,K,V (co32 x w128) -> LDS scratch [c][wl]; 2-head Gram -> atomics; V out ----
  u16* scrQ = (u16*)wq;
  u16* scrK = (u16*)(wq + 8192);
  u16* scrV = (u16*)(wq + 16384);
#pragma unroll
  for (int mi = 0; mi < 2; ++mi)
#pragma unroll
    for (int ni = 0; ni < 2; ++ni)
#pragma unroll
      for (int r = 0; r < 4; ++r) {
        int cc = mi * 16 + (lane >> 4) * 4 + r;       // 0..31
        int wl = n0l + ni * 16 + (lane & 15);         // 0..127
        scrQ[cc * 128 + wl] = f2h(aq[mi][ni][r]);
        scrK[cc * 128 + wl] = f2h(ak[mi][ni][r]);
        scrV[cc * 128 + wl] = f2h(av[mi][ni][r]);
      }
  __syncthreads();
  {
    int hdl = wv >> 1;                          // local head (0/1)
    int wp = wv & 1;                            // wave-pair half of the contraction
    int hdg = coq * 2 + hdl;                    // global head
    f32x4 g = {};
#pragma unroll
    for (int k2 = 0; k2 < 2; ++k2) {            // this wave: 64 of 128 (ci,wg) slots
      PK A, Bq;
#pragma unroll
      for (int jj = 0; jj < 8; ++jj) {
        int k = (lane >> 4) * 8 + jj;           // 0..31
        int slot = (wp * 2 + k2) * 32 + k;      // 0..127
        int ci = slot >> 3, wg = slot & 7;
        A.u[jj]  = scrK[(hdl * 16 + ci) * 128 + wg * 16 + (lane & 15)];
        Bq.u[jj] = scrQ[(hdl * 16 + ci) * 128 + wg * 16 + (lane & 15)];
      }
      g = mfma16(A.i, Bq.i, g);
    }
#pragma unroll
    for (int r = 0; r < 4; ++r)
      atomicAdd(&attnb[((b * 8 + hdg) * 16 + (lane >> 4) * 4 + r) * 16 + (lane & 15)], g[r]);
  }
  char* dstV = (char*)Vc + (size_t)(b * 128 + coq * 32) * 32768 + (size_t)h * 256;
#pragma unroll
  for (int i = 0; i < 2; ++i) {
    int gi = i * 256 + tid;                     // 0..511
    int c = gi >> 4, off = (gi & 15) << 4;      // 32 rows x 256B
    *(int4*)(dstV + (size_t)c * 32768 + off) = *(const int4*)((const char*)scrV + c * 256 + off);
  }
}

// ---------------- K4: softmax + fold wo: W2[b][co][k=hd*16+dd] (f16, swizzled) --------------------
__global__ __launch_bounds__(256) void k_w2(const float* __restrict__ attnb,
    const void* __restrict__ wo, const void* __restrict__ scale,
    const u16* __restrict__ xdet, u16* __restrict__ w2s) {
  __shared__ float P[256];
  int b = blockIdx.x, hd = blockIdx.y;
  int tid = threadIdx.x;
  int isf = detect_isf(xdet, tid, 256);
  float sc = isf ? ((const float*)scale)[0] : b2f(((const u16*)scale)[0]);
  float inv_sc = 1.f / sc;
  P[tid] = attnb[(b * 8 + hd) * 256 + tid] * inv_sc;
  __syncthreads();
  if (tid < 16) {
    int dk = tid;
    float m = -1e30f;
#pragma unroll
    for (int j = 0; j < 16; ++j) m = fmaxf(m, P[dk * 16 + j]);
    float e[16]; float s = 0.f;
#pragma unroll
    for (int j = 0; j < 16; ++j) { e[j] = expf(P[dk * 16 + j] - m); s += e[j]; }
    float is = 1.f / s;
#pragma unroll
    for (int j = 0; j < 16; ++j) P[dk * 16 + j] = e[j] * is;
  }
  __syncthreads();
  int co = tid & 127, kg = tid >> 7;
  float wr[16];
  if (isf) {
    const float* wof = (const float*)wo;
#pragma unroll
    for (int d = 0; d < 16; ++d) wr[d] = wof[co * 128 + hd * 16 + d];
  } else {
    const u16* wou = (const u16*)wo;
#pragma unroll
    for (int d = 0; d < 16; ++d) wr[d] = b2f(wou[co * 128 + hd * 16 + d]);
  }
  PK p;
#pragma unroll
  for (int j = 0; j < 8; ++j) {
    int dd = kg * 8 + j;
    float a = 0.f;
#pragma unroll
    for (int d = 0; d < 16; ++d) a += wr[d] * P[dd * 16 + d];
    p.u[j] = f2h(a);
  }
  int slot = hd * 2 + kg;
  *(int4*)((char*)w2s + (size_t)b * 32768 + co * 256 + ((slot ^ (co & 7)) << 4)) = p.i;
}

// ---------------- K5: out = W2 @ Vbrick + x, w-split (b,h,whalf), 2 blocks/CU ---------------------
__global__ __launch_bounds__(256, 2) void k_final(const u16* __restrict__ w2s,
    const u16* __restrict__ Vc, const void* __restrict__ xr, void* __restrict__ outr) {
  __shared__ __align__(16) char sW[32768];
  __shared__ __align__(16) char sBk[16384];     // 64 brick rows x 256B
  int tid = threadIdx.x, lane = tid & 63, wv = tid >> 6;
  int bi = blockIdx.x;
  int whalf = bi & 1, h = (bi >> 1) & 127, b = bi >> 8;
  int isf = detect_isf((const u16*)xr, tid, 256);
  const char* wsrc = (const char*)w2s + (size_t)b * 32768;
#pragma unroll
  for (int i = 0; i < 8; ++i) {
    int off = i * 4096 + tid * 16;
    gload16(wsrc + off, sW + off);
  }
#pragma unroll
  for (int i = 0; i < 4; ++i) {                 // V brick: 64 gathered rows for this w-half
    int gi = i * 256 + tid;                     // 0..1023
    int lr = gi >> 4, chunk = gi & 15;
    int hd8 = lr >> 3, rl = whalf * 8 + (lr & 7);
    int cv = hd8 * 16 + (h >> 3);
    int hv = (h & 7) * 16 + rl;
    const char* src = (const char*)Vc + (size_t)(b * 128 + cv) * 32768 + (size_t)hv * 256 + (chunk << 4);
    gload16(src, sBk + gi * 16);
  }
  __syncthreads();
  int m0 = (wv >> 1) * 64, n0l = (wv & 1) * 32;
  f32x4 acc[4][2] = {};
#pragma unroll
  for (int k0i = 0; k0i < 4; ++k0i) {
    int4 af[4], bfr[2];
#pragma unroll
    for (int mi = 0; mi < 4; ++mi) {
      int cc = m0 + mi * 16 + (lane & 15);
      int slot = (k0i * 4 + (lane >> 4)) ^ (cc & 7);
      af[mi] = *(const int4*)(sW + cc * 256 + (slot << 4));
    }
#pragma unroll
    for (int ni = 0; ni < 2; ++ni) {
      int wl = n0l + ni * 16 + (lane & 15);
      int k = k0i * 32 + (lane >> 4) * 8;
      int hd8 = k >> 4, dd0 = k & 15;
      bfr[ni] = *(const int4*)(sBk + (hd8 * 8 + (wl >> 3)) * 256 + ((wl & 7) * 32 + dd0 * 2));
    }
#pragma unroll
    for (int mi = 0; mi < 4; ++mi)
#pragma unroll
      for (int ni = 0; ni < 2; ++ni)
        acc[mi][ni] = mfma16(af[mi], bfr[ni], acc[mi][ni]);
  }
  if (isf) {
    const float* xf = (const float*)xr;
    float* of = (float*)outr;
#pragma unroll
    for (int mi = 0; mi < 4; ++mi)
#pragma unroll
      for (int ni = 0; ni < 2; ++ni) {
        int w = whalf * 64 + n0l + ni * 16 + (lane & 15);
#pragma unroll
        for (int r = 0; r < 4; ++r) {
          int cc = m0 + mi * 16 + (lane >> 4) * 4 + r;
          size_t idx = ((size_t)(b * 128 + cc) * 128 + (size_t)h) * 128 + w;
          of[idx] = acc[mi][ni][r] + xf[idx];
        }
      }
  } else {
    const u16* xu = (const u16*)xr;
    u16* ou = (u16*)outr;
#pragma unroll
    for (int mi = 0; mi < 4; ++mi)
#pragma unroll
      for (int ni = 0; ni < 2; ++ni) {
        int w = whalf * 64 + n0l + ni * 16 + (lane & 15);
#pragma unroll
        for (int r = 0; r < 4; ++r) {
          int cc = m0 + mi * 16 + (lane >> 4) * 4 + r;
          size_t idx = ((size_t)(b * 128 + cc) * 128 + (size_t)h) * 128 + w;
          ou[idx] = f2b(acc[mi][ni][r] + b2f(xu[idx]));
        }
      }
  }
}

extern "C" void kernel_launch(void* const* d_in, const int* in_sizes, int n_in,
                              void* d_out, int out_size, void* d_ws, size_t ws_size,
                              hipStream_t stream) {
  (void)in_sizes; (void)n_in; (void)out_size; (void)ws_size;
  const void* x     = d_in[0];
  const void* gamma = d_in[1];
  const void* beta  = d_in[2];
  const void* scale = d_in[3];
  const void* w1q = d_in[4];
  const void* w2q = d_in[5];
  const void* w1k = d_in[6];
  const void* w2k = d_in[7];
  const void* w1v = d_in[8];
  const void* w2v = d_in[9];
  const void* wo  = d_in[10];
  char* ws = (char*)d_ws;
  u16* xnt     = (u16*)(ws);                           // 8.66 MB padded frag-major f16
  u16* weff    = (u16*)(ws + (9u << 20));              // 864 KB fused 3x3 weights f16, frag-major
  u16* Vc      = (u16*)(ws + (10u << 20));             // 8 MB [b][c][h][w] f16 linear
  float* attnb = (float*)(ws + (18u << 20));           // 16 KB f32 (zeroed by LN block)
  u16* w2s     = (u16*)(ws + (18u << 20) + 65536);     // 64 KB f16, swizzled

  hipLaunchKernelGGL(k_lnweff, dim3(287), dim3(256), 0, stream,
                     x, gamma, beta, w1q, w2q, w1k, w2k, w1v, w2v, weff, xnt, attnb);
  hipLaunchKernelGGL(k_conv, dim3(1024), dim3(256), 0, stream, xnt, weff, Vc, attnb);
  hipLaunchKernelGGL(k_w2, dim3(2, 8), dim3(256), 0, stream, attnb, wo, scale, (const u16*)x, w2s);
  hipLaunchKernelGGL(k_final, dim3(512), dim3(256), 0, stream, w2s, Vc, x, d_out);
}

// Round 24
// 93.663 us; speedup vs baseline: 2.0753x; 2.0753x over previous
//
#include <hip/hip_runtime.h>
#include <hip/hip_bf16.h>

typedef unsigned short u16;
typedef _Float16 f16;
typedef f16 f16x8 __attribute__((ext_vector_type(8)));
typedef float f32x4 __attribute__((ext_vector_type(4)));

__device__ __forceinline__ float b2f(u16 u) {
  unsigned v = (unsigned)u << 16; float f; __builtin_memcpy(&f, &v, 4); return f;
}
__device__ __forceinline__ u16 f2b(float f) {
  return __builtin_bit_cast(u16, __float2bfloat16(f));
}
__device__ __forceinline__ float h2f(u16 u) {
  return (float)__builtin_bit_cast(f16, u);
}
__device__ __forceinline__ u16 f2h(float f) {
  return __builtin_bit_cast(u16, (f16)f);
}
__device__ __forceinline__ void gload16(const void* g, void* l) {
  __builtin_amdgcn_global_load_lds((__attribute__((address_space(1))) void*)(const_cast<void*>(g)),
                                   (__attribute__((address_space(3))) void*)l, 16, 0, 0);
}
__device__ __forceinline__ f32x4 mfma16(int4 a, int4 b, f32x4 c) {
  return __builtin_amdgcn_mfma_f32_16x16x32_f16(__builtin_bit_cast(f16x8, a),
                                                __builtin_bit_cast(f16x8, b), c, 0, 0, 0);
}
union PK { int4 i; u16 u[8]; };

// Self dtype detect: sample 1024 even u16s of x; f32 buffer -> ~44% have exp-field>=0x90, bf16 -> 0.
__device__ __forceinline__ int detect_isf(const u16* x, int tid, int nthr) {
  __shared__ int dcnt;
  if (tid == 0) dcnt = 0;
  __syncthreads();
  int c = 0;
  for (int i = tid; i < 1024; i += nthr) {
    u16 u = x[i * 2];
    if (((u >> 7) & 0xFF) >= 0x90) ++c;
  }
  if (c) atomicAdd(&dcnt, c);
  __syncthreads();
  return dcnt > 16;
}

// xnt padded frag-major layout: row (b*130 + h+1), 2080 chunks of 16B; chunk = g*130 + (w+1);
// chunk holds xn[c = g*8 .. g*8+8) at column w. Pad rows (h=-1,128) and pad cols (w=-1,128) zero.
#define XROW 33280

// ---------------- K0+K1 merged: blocks 0..26 build weff (frag-major); blocks 27..282 LayerNorm
// rows; blocks 283..286 zero pad rows; LN block 27 also zeroes attnb.
__global__ __launch_bounds__(256) void k_lnweff(
    const void* __restrict__ xr, const void* __restrict__ gr, const void* __restrict__ br_,
    const void* __restrict__ w1q, const void* __restrict__ w2q,
    const void* __restrict__ w1k, const void* __restrict__ w2k,
    const void* __restrict__ w1v, const void* __restrict__ w2v,
    u16* __restrict__ weff, u16* __restrict__ xnt, float* __restrict__ attnb) {
  __shared__ __align__(16) char smem[99328];   // overlay: weff path 64KB; LN path 97KB
  int tid = threadIdx.x;
  int bi = blockIdx.x;

  if (bi < 27) {
    u16* sA = (u16*)smem;                      // w2t [c][m ^ 8*(c&15)]
    u16* sB = (u16*)(smem + 32768);            // w1t [ci][m ^ 8*(ci&15)]
    int isf = detect_isf((const u16*)xr, tid, 256);
    int blk = bi;                              // tap*3 + br
    int tap = blk / 3, br = blk - tap * 3;
    const void* w1 = br == 0 ? w1q : (br == 1 ? w1k : w1v);
    const void* w2 = br == 0 ? w2q : (br == 1 ? w2k : w2v);
    if (isf) {
      const float* w2f = (const float*)w2;
      const float* w1f = (const float*)w1;
#pragma unroll 4
      for (int i = 0; i < 64; ++i) {
        int e = i * 256 + tid;
        int c = e >> 7, m = e & 127;
        sA[c * 128 + (m ^ ((c & 15) << 3))] = f2h(w2f[e * 9 + tap]);
        int ci = e & 127;
        sB[ci * 128 + ((e >> 7) ^ ((ci & 15) << 3))] = f2h(w1f[e]);
      }
    } else {
      const u16* w2u = (const u16*)w2;
      const u16* w1u = (const u16*)w1;
#pragma unroll 4
      for (int i = 0; i < 64; ++i) {
        int e = i * 256 + tid;
        int c = e >> 7, m = e & 127;
        sA[c * 128 + (m ^ ((c & 15) << 3))] = f2h(b2f(w2u[e * 9 + tap]));
        int ci = e & 127;
        sB[ci * 128 + ((e >> 7) ^ ((ci & 15) << 3))] = f2h(b2f(w1u[e]));
      }
    }
    __syncthreads();
    int lane = tid & 63, wv = tid >> 6;
    int m0w = (wv >> 1) * 64, n0w = (wv & 1) * 64;   // c-range, ci-range
    f32x4 acc[4][4] = {};
#pragma unroll
    for (int k0 = 0; k0 < 4; ++k0) {
      int mrow = k0 * 32 + (lane >> 4) * 8;
      int4 a4[4], b4[4];
#pragma unroll
      for (int mi = 0; mi < 4; ++mi) {
        int c = m0w + mi * 16 + (lane & 15);
        a4[mi] = *(const int4*)&sA[c * 128 + (mrow ^ ((c & 15) << 3))];
      }
#pragma unroll
      for (int ni = 0; ni < 4; ++ni) {
        int ci = n0w + ni * 16 + (lane & 15);
        b4[ni] = *(const int4*)&sB[ci * 128 + (mrow ^ ((ci & 15) << 3))];
      }
#pragma unroll
      for (int mi = 0; mi < 4; ++mi)
#pragma unroll
        for (int ni = 0; ni < 4; ++ni)
          acc[mi][ni] = mfma16(a4[mi], b4[ni], acc[mi][ni]);
    }
    __syncthreads();
#pragma unroll
    for (int mi = 0; mi < 4; ++mi)
#pragma unroll
      for (int ni = 0; ni < 4; ++ni) {
#pragma unroll
        for (int r = 0; r < 4; ++r) {
          int c = m0w + mi * 16 + (lane >> 4) * 4 + r;
          int ci = n0w + ni * 16 + (lane & 15);
          sA[c * 128 + ci] = f2h(acc[mi][ni][r]);    // LDS linear [c][ci]
        }
      }
    __syncthreads();
    int4* dst = (int4*)((char*)weff + (size_t)blk * 32768);
#pragma unroll
    for (int i = 0; i < 8; ++i) {
      int gidx = i * 256 + tid;
      int k0 = gidx >> 9;
      int ch = gidx & 511;
      int mt = ch >> 6, l = ch & 63;
      int c = mt * 16 + (l & 15);
      int g = k0 * 4 + (l >> 4);
      dst[gidx] = *(const int4*)((const char*)sA + c * 256 + g * 16);
    }
    return;
  }

  int li = bi - 27;                            // 0..259
  if (li >= 256) {                             // pad-row zeroing blocks
    int pid = li - 256;
    int b = pid >> 1, row = (pid & 1) ? 129 : 0;
    char* rbase = (char*)xnt + (size_t)(b * 130 + row) * XROW;
    int4 z = make_int4(0, 0, 0, 0);
    for (int i = 0; i < 9; ++i) {
      int idx = i * 256 + tid;
      if (idx < 2080) *(int4*)(rbase + idx * 16) = z;
    }
    return;
  }
  if (li == 0) {
    for (int i = tid; i < 4096; i += 256) attnb[i] = 0.f;
  }
  float* sx = (float*)smem;                    // 64KB raw f32 x, [c][chunk], phys = logical^(c&31)
  u16* sn = (u16*)(smem + 65536);              // 32KB f16 xn, [w][chunk g^(w&15)]
  float* sg = (float*)(smem + 98304);
  float* sb = (float*)(smem + 98816);
  int b = li >> 7, h = li & 127;
  int isf = detect_isf((const u16*)xr, tid, 256);
  if (tid < 128) {
    sg[tid] = isf ? ((const float*)gr)[tid] : b2f(((const u16*)gr)[tid]);
    sb[tid] = isf ? ((const float*)br_)[tid] : b2f(((const u16*)br_)[tid]);
  }
  if (isf) {
#pragma unroll
    for (int it = 0; it < 16; ++it) {
      int d = it * 4096 + tid * 16;
      int c = d >> 9;
      int p = (d >> 4) & 31;
      int sc = p ^ (c & 31);
      const char* src = (const char*)xr + (size_t)(b * 128 + c) * 65536 + (size_t)h * 512 + (sc << 4);
      gload16(src, (char*)sx + d);
    }
  } else {
    int c = tid >> 1, half = tid & 1;
    const u16* xu = (const u16*)xr + ((size_t)(b * 128 + c) * 128 + h) * 128 + half * 64;
    for (int i = 0; i < 16; ++i) {
      int phys = (half * 16 + i) ^ (c & 31);
      float* dst = sx + c * 128 + phys * 4;
#pragma unroll
      for (int j = 0; j < 4; ++j) dst[j] = b2f(xu[i * 4 + j]);
    }
  }
  __syncthreads();
  int c = tid >> 1, half = tid & 1;
  float sum = 0.f, sq = 0.f;
#pragma unroll
  for (int i = 0; i < 16; ++i) {
    int phys = (half * 16 + i) ^ (c & 31);
    const float* v = sx + c * 128 + phys * 4;
#pragma unroll
    for (int j = 0; j < 4; ++j) { float f = v[j]; sum += f; sq += f * f; }
  }
  sum += __shfl_xor(sum, 1);
  sq  += __shfl_xor(sq, 1);
  float mu = sum * 0.0078125f;
  float var = sq * 0.0078125f - mu * mu;
  float rs = rsqrtf(var + 1e-5f);
  int cg = c >> 3, cl = c & 7;
#pragma unroll
  for (int i = 0; i < 16; ++i) {
    int logical = half * 16 + i;
    int phys = logical ^ (c & 31);
    const float* v = sx + c * 128 + phys * 4;
#pragma unroll
    for (int j = 0; j < 4; ++j) {
      int w = logical * 4 + j;
      sn[w * 128 + (((cg ^ (w & 15)) << 3) | cl)] = f2h((v[j] - mu) * rs * sg[w] + sb[w]);
    }
  }
  __syncthreads();
  char* obase = (char*)xnt + (size_t)(b * 130 + h + 1) * XROW;
#pragma unroll
  for (int i = 0; i < 8; ++i) {
    int idx = i * 256 + tid;
    int g = idx >> 7, w = idx & 127;
    int phys = g ^ (w & 15);
    *(int4*)(obase + (g * 130 + w + 1) * 16) = *(const int4*)((const char*)sn + w * 256 + (phys << 4));
  }
  if (tid < 32) {
    int g = tid >> 1, side = tid & 1;
    *(int4*)(obase + (g * 130 + (side ? 129 : 0)) * 16) = make_int4(0, 0, 0, 0);
  }
}

// ---------------- K2: Q,K,V eff-3x3 conv, CO-QUARTER split (block = b,h,coq: co 32 x w 128).
// 1024 blocks; natural VGPR allocation (~110) gives 4 blocks/CU via LDS 24KB + VGPR budget.
// 8KB/tile staged, 2x8KB dbuf. 27 steps x 16 MFMA/wave, plain __syncthreads. bc per tap (L2-hot).
// Fused per-head Gram (2 heads/block, wave-pair split) -> f32 atomics.
#define STAGE_T(T, BUF) do { \
    const char* base_ = (const char*)weff + (size_t)(T) * 32768 + (size_t)coq * 2048; \
    char* dst_ = wq + (BUF) * 8192; \
    _Pragma("unroll") \
    for (int i_ = 0; i_ < 2; ++i_) \
      gload16(base_ + (size_t)(i_ * 2 + (tid >> 7)) * 8192 + (tid & 127) * 16, \
              dst_ + i_ * 4096 + tid * 16); \
  } while (0)

#define BC_LOAD(DST, T6) do { \
    int dy_ = (T6) / 3, dx_ = (T6) % 3; \
    const char* rb_ = (const char*)xnt + (size_t)(b * 130 + h + dy_) * XROW; \
    _Pragma("unroll") \
    for (int kk = 0; kk < 4; ++kk) \
      _Pragma("unroll") \
      for (int ni = 0; ni < 2; ++ni) { \
        int wp1 = n0l + ni * 16 + (lane & 15) + dx_;   /* w+1, always 0..129 */ \
        int chunk = (kk * 4 + (lane >> 4)) * 130 + wp1; \
        DST[kk][ni] = *(const int4*)(rb_ + chunk * 16); \
      } \
  } while (0)

#define QFULL(ACC, QB) do { \
    _Pragma("unroll") \
    for (int k0 = 0; k0 < 4; ++k0) { \
      int4 af[2]; \
      _Pragma("unroll") \
      for (int mi = 0; mi < 2; ++mi) \
        af[mi] = *(const int4*)((QB) + (k0 >> 1) * 4096 + (k0 & 1) * 2048 + mi * 1024 + lane * 16); \
      _Pragma("unroll") \
      for (int mi = 0; mi < 2; ++mi) { \
        ACC[mi][0] = mfma16(af[mi], bcA[k0][0], ACC[mi][0]); \
        ACC[mi][1] = mfma16(af[mi], bcA[k0][1], ACC[mi][1]); \
      } \
    } \
  } while (0)

__global__ __launch_bounds__(256, 2) void k_conv(const u16* __restrict__ xnt,
    const u16* __restrict__ weff, u16* __restrict__ Vc, float* __restrict__ attnb) {
  __shared__ __align__(16) char wq[24576];      // 2x8KB dbuf; epilogue scrQ/K/V 24KB
  int tid = threadIdx.x, lane = tid & 63, wv = tid >> 6;
  int bi = blockIdx.x;
  int coq = bi & 3, h = (bi >> 2) & 127, b = bi >> 9;
  int n0l = wv * 32;                            // wave's w range (32 of 128)

  int4 bcA[4][2];
  BC_LOAD(bcA, 0);
  STAGE_T(0, 0);
  __syncthreads();

  f32x4 aq[2][2] = {}, ak[2][2] = {}, av[2][2] = {};

  for (int t = 0; t < 27; ++t) {                // t = tap*3 + br
    int br = t % 3, tgrp = t / 3;
    if (t + 1 < 27) STAGE_T(t + 1, (t + 1) & 1);     // prefetch next co-quarter tile
    if (br == 0 && tgrp > 0) BC_LOAD(bcA, tgrp);     // fresh tap fragments (L2-hot, TLP-hidden)
    const char* qb = wq + (t & 1) * 8192;
    if (br == 0)      QFULL(aq, qb);
    else if (br == 1) QFULL(ak, qb);
    else              QFULL(av, qb);
    __syncthreads();                            // drains prefetch; protects buffer reuse
  }
  // ---- epilogue: Q,K,V (co32 x w128) -> LDS scratch [c][wl]; 2-head Gram -> atomics; V out ----
  u16* scrQ = (u16*)wq;
  u16* scrK = (u16*)(wq + 8192);
  u16* scrV = (u16*)(wq + 16384);
#pragma unroll
  for (int mi = 0; mi < 2; ++mi)
#pragma unroll
    for (int ni = 0; ni < 2; ++ni)
#pragma unroll
      for (int r = 0; r < 4; ++r) {
        int cc = mi * 16 + (lane >> 4) * 4 + r;       // 0..31
        int wl = n0l + ni * 16 + (lane & 15);         // 0..127
        scrQ[cc * 128 + wl] = f2h(aq[mi][ni][r]);
        scrK[cc * 128 + wl] = f2h(ak[mi][ni][r]);
        scrV[cc * 128 + wl] = f2h(av[mi][ni][r]);
      }
  __syncthreads();
  {
    int hdl = wv >> 1;                          // local head (0/1)
    int wp = wv & 1;                            // wave-pair half of the contraction
    int hdg = coq * 2 + hdl;                    // global head
    f32x4 g = {};
#pragma unroll
    for (int k2 = 0; k2 < 2; ++k2) {            // this wave: 64 of 128 (ci,wg) slots
      PK A, Bq;
#pragma unroll
      for (int jj = 0; jj < 8; ++jj) {
        int k = (lane >> 4) * 8 + jj;           // 0..31
        int slot = (wp * 2 + k2) * 32 + k;      // 0..127
        int ci = slot >> 3, wg = slot & 7;
        A.u[jj]  = scrK[(hdl * 16 + ci) * 128 + wg * 16 + (lane & 15)];
        Bq.u[jj] = scrQ[(hdl * 16 + ci) * 128 + wg * 16 + (lane & 15)];
      }
      g = mfma16(A.i, Bq.i, g);
    }
#pragma unroll
    for (int r = 0; r < 4; ++r)
      atomicAdd(&attnb[((b * 8 + hdg) * 16 + (lane >> 4) * 4 + r) * 16 + (lane & 15)], g[r]);
  }
  char* dstV = (char*)Vc + (size_t)(b * 128 + coq * 32) * 32768 + (size_t)h * 256;
#pragma unroll
  for (int i = 0; i < 2; ++i) {
    int gi = i * 256 + tid;                     // 0..511
    int c = gi >> 4, off = (gi & 15) << 4;      // 32 rows x 256B
    *(int4*)(dstV + (size_t)c * 32768 + off) = *(const int4*)((const char*)scrV + c * 256 + off);
  }
}

// ---------------- K4: softmax + fold wo: W2[b][co][k=hd*16+dd] (f16, swizzled) --------------------
__global__ __launch_bounds__(256) void k_w2(const float* __restrict__ attnb,
    const void* __restrict__ wo, const void* __restrict__ scale,
    const u16* __restrict__ xdet, u16* __restrict__ w2s) {
  __shared__ float P[256];
  int b = blockIdx.x, hd = blockIdx.y;
  int tid = threadIdx.x;
  int isf = detect_isf(xdet, tid, 256);
  float sc = isf ? ((const float*)scale)[0] : b2f(((const u16*)scale)[0]);
  float inv_sc = 1.f / sc;
  P[tid] = attnb[(b * 8 + hd) * 256 + tid] * inv_sc;
  __syncthreads();
  if (tid < 16) {
    int dk = tid;
    float m = -1e30f;
#pragma unroll
    for (int j = 0; j < 16; ++j) m = fmaxf(m, P[dk * 16 + j]);
    float e[16]; float s = 0.f;
#pragma unroll
    for (int j = 0; j < 16; ++j) { e[j] = expf(P[dk * 16 + j] - m); s += e[j]; }
    float is = 1.f / s;
#pragma unroll
    for (int j = 0; j < 16; ++j) P[dk * 16 + j] = e[j] * is;
  }
  __syncthreads();
  int co = tid & 127, kg = tid >> 7;
  float wr[16];
  if (isf) {
    const float* wof = (const float*)wo;
#pragma unroll
    for (int d = 0; d < 16; ++d) wr[d] = wof[co * 128 + hd * 16 + d];
  } else {
    const u16* wou = (const u16*)wo;
#pragma unroll
    for (int d = 0; d < 16; ++d) wr[d] = b2f(wou[co * 128 + hd * 16 + d]);
  }
  PK p;
#pragma unroll
  for (int j = 0; j < 8; ++j) {
    int dd = kg * 8 + j;
    float a = 0.f;
#pragma unroll
    for (int d = 0; d < 16; ++d) a += wr[d] * P[dd * 16 + d];
    p.u[j] = f2h(a);
  }
  int slot = hd * 2 + kg;
  *(int4*)((char*)w2s + (size_t)b * 32768 + co * 256 + ((slot ^ (co & 7)) << 4)) = p.i;
}

// ---------------- K5: out = W2 @ Vbrick + x, w-split (b,h,whalf), 2 blocks/CU ---------------------
__global__ __launch_bounds__(256, 2) void k_final(const u16* __restrict__ w2s,
    const u16* __restrict__ Vc, const void* __restrict__ xr, void* __restrict__ outr) {
  __shared__ __align__(16) char sW[32768];
  __shared__ __align__(16) char sBk[16384];     // 64 brick rows x 256B
  int tid = threadIdx.x, lane = tid & 63, wv = tid >> 6;
  int bi = blockIdx.x;
  int whalf = bi & 1, h = (bi >> 1) & 127, b = bi >> 8;
  int isf = detect_isf((const u16*)xr, tid, 256);
  const char* wsrc = (const char*)w2s + (size_t)b * 32768;
#pragma unroll
  for (int i = 0; i < 8; ++i) {
    int off = i * 4096 + tid * 16;
    gload16(wsrc + off, sW + off);
  }
#pragma unroll
  for (int i = 0; i < 4; ++i) {                 // V brick: 64 gathered rows for this w-half
    int gi = i * 256 + tid;                     // 0..1023
    int lr = gi >> 4, chunk = gi & 15;
    int hd8 = lr >> 3, rl = whalf * 8 + (lr & 7);
    int cv = hd8 * 16 + (h >> 3);
    int hv = (h & 7) * 16 + rl;
    const char* src = (const char*)Vc + (size_t)(b * 128 + cv) * 32768 + (size_t)hv * 256 + (chunk << 4);
    gload16(src, sBk + gi * 16);
  }
  __syncthreads();
  int m0 = (wv >> 1) * 64, n0l = (wv & 1) * 32;
  f32x4 acc[4][2] = {};
#pragma unroll
  for (int k0i = 0; k0i < 4; ++k0i) {
    int4 af[4], bfr[2];
#pragma unroll
    for (int mi = 0; mi < 4; ++mi) {
      int cc = m0 + mi * 16 + (lane & 15);
      int slot = (k0i * 4 + (lane >> 4)) ^ (cc & 7);
      af[mi] = *(const int4*)(sW + cc * 256 + (slot << 4));
    }
#pragma unroll
    for (int ni = 0; ni < 2; ++ni) {
      int wl = n0l + ni * 16 + (lane & 15);
      int k = k0i * 32 + (lane >> 4) * 8;
      int hd8 = k >> 4, dd0 = k & 15;
      bfr[ni] = *(const int4*)(sBk + (hd8 * 8 + (wl >> 3)) * 256 + ((wl & 7) * 32 + dd0 * 2));
    }
#pragma unroll
    for (int mi = 0; mi < 4; ++mi)
#pragma unroll
      for (int ni = 0; ni < 2; ++ni)
        acc[mi][ni] = mfma16(af[mi], bfr[ni], acc[mi][ni]);
  }
  if (isf) {
    const float* xf = (const float*)xr;
    float* of = (float*)outr;
#pragma unroll
    for (int mi = 0; mi < 4; ++mi)
#pragma unroll
      for (int ni = 0; ni < 2; ++ni) {
        int w = whalf * 64 + n0l + ni * 16 + (lane & 15);
#pragma unroll
        for (int r = 0; r < 4; ++r) {
          int cc = m0 + mi * 16 + (lane >> 4) * 4 + r;
          size_t idx = ((size_t)(b * 128 + cc) * 128 + (size_t)h) * 128 + w;
          of[idx] = acc[mi][ni][r] + xf[idx];
        }
      }
  } else {
    const u16* xu = (const u16*)xr;
    u16* ou = (u16*)outr;
#pragma unroll
    for (int mi = 0; mi < 4; ++mi)
#pragma unroll
      for (int ni = 0; ni < 2; ++ni) {
        int w = whalf * 64 + n0l + ni * 16 + (lane & 15);
#pragma unroll
        for (int r = 0; r < 4; ++r) {
          int cc = m0 + mi * 16 + (lane >> 4) * 4 + r;
          size_t idx = ((size_t)(b * 128 + cc) * 128 + (size_t)h) * 128 + w;
          ou[idx] = f2b(acc[mi][ni][r] + b2f(xu[idx]));
        }
      }
  }
}

extern "C" void kernel_launch(void* const* d_in, const int* in_sizes, int n_in,
                              void* d_out, int out_size, void* d_ws, size_t ws_size,
                              hipStream_t stream) {
  (void)in_sizes; (void)n_in; (void)out_size; (void)ws_size;
  const void* x     = d_in[0];
  const void* gamma = d_in[1];
  const void* beta  = d_in[2];
  const void* scale = d_in[3];
  const void* w1q = d_in[4];
  const void* w2q = d_in[5];
  const void* w1k = d_in[6];
  const void* w2k = d_in[7];
  const void* w1v = d_in[8];
  const void* w2v = d_in[9];
  const void* wo  = d_in[10];
  char* ws = (char*)d_ws;
  u16* xnt     = (u16*)(ws);                           // 8.66 MB padded frag-major f16
  u16* weff    = (u16*)(ws + (9u << 20));              // 864 KB fused 3x3 weights f16, frag-major
  u16* Vc      = (u16*)(ws + (10u << 20));             // 8 MB [b][c][h][w] f16 linear
  float* attnb = (float*)(ws + (18u << 20));           // 16 KB f32 (zeroed by LN block)
  u16* w2s     = (u16*)(ws + (18u << 20) + 65536);     // 64 KB f16, swizzled

  hipLaunchKernelGGL(k_lnweff, dim3(287), dim3(256), 0, stream,
                     x, gamma, beta, w1q, w2q, w1k, w2k, w1v, w2v, weff, xnt, attnb);
  hipLaunchKernelGGL(k_conv, dim3(1024), dim3(256), 0, stream, xnt, weff, Vc, attnb);
  hipLaunchKernelGGL(k_w2, dim3(2, 8), dim3(256), 0, stream, attnb, wo, scale, (const u16*)x, w2s);
  hipLaunchKernelGGL(k_final, dim3(512), dim3(256), 0, stream, w2s, Vc, x, d_out);
}

// Round 25
// 79.422 us; speedup vs baseline: 2.4474x; 1.1793x over previous
//
#include <hip/hip_runtime.h>
#include <hip/hip_bf16.h>

typedef unsigned short u16;
typedef _Float16 f16;
typedef f16 f16x8 __attribute__((ext_vector_type(8)));
typedef float f32x4 __attribute__((ext_vector_type(4)));

__device__ __forceinline__ float b2f(u16 u) {
  unsigned v = (unsigned)u << 16; float f; __builtin_memcpy(&f, &v, 4); return f;
}
__device__ __forceinline__ u16 f2b(float f) {
  return __builtin_bit_cast(u16, __float2bfloat16(f));
}
__device__ __forceinline__ float h2f(u16 u) {
  return (float)__builtin_bit_cast(f16, u);
}
__device__ __forceinline__ u16 f2h(float f) {
  return __builtin_bit_cast(u16, (f16)f);
}
__device__ __forceinline__ void gload16(const void* g, void* l) {
  __builtin_amdgcn_global_load_lds((__attribute__((address_space(1))) void*)(const_cast<void*>(g)),
                                   (__attribute__((address_space(3))) void*)l, 16, 0, 0);
}
__device__ __forceinline__ f32x4 mfma16(int4 a, int4 b, f32x4 c) {
  return __builtin_amdgcn_mfma_f32_16x16x32_f16(__builtin_bit_cast(f16x8, a),
                                                __builtin_bit_cast(f16x8, b), c, 0, 0, 0);
}
union PK { int4 i; u16 u[8]; };

// Self dtype detect: sample 1024 even u16s of x; f32 buffer -> ~44% have exp-field>=0x90, bf16 -> 0.
__device__ __forceinline__ int detect_isf(const u16* x, int tid, int nthr) {
  __shared__ int dcnt;
  if (tid == 0) dcnt = 0;
  __syncthreads();
  int c = 0;
  for (int i = tid; i < 1024; i += nthr) {
    u16 u = x[i * 2];
    if (((u >> 7) & 0xFF) >= 0x90) ++c;
  }
  if (c) atomicAdd(&dcnt, c);
  __syncthreads();
  return dcnt > 16;
}

// xnt padded frag-major layout: row (b*130 + h+1), 2080 chunks of 16B; chunk = g*130 + (w+1);
// chunk holds xn[c = g*8 .. g*8+8) at column w. Pad rows (h=-1,128) and pad cols (w=-1,128) zero.
#define XROW 33280

// ---------------- K0+K1 merged: blocks 0..26 build weff (frag-major); blocks 27..282 LayerNorm
// rows; blocks 283..286 zero pad rows; LN block 27 also zeroes attnb.
__global__ __launch_bounds__(256) void k_lnweff(
    const void* __restrict__ xr, const void* __restrict__ gr, const void* __restrict__ br_,
    const void* __restrict__ w1q, const void* __restrict__ w2q,
    const void* __restrict__ w1k, const void* __restrict__ w2k,
    const void* __restrict__ w1v, const void* __restrict__ w2v,
    u16* __restrict__ weff, u16* __restrict__ xnt, float* __restrict__ attnb) {
  __shared__ __align__(16) char smem[99328];   // overlay: weff path 64KB; LN path 97KB
  int tid = threadIdx.x;
  int bi = blockIdx.x;

  if (bi < 27) {
    u16* sA = (u16*)smem;                      // w2t [c][m ^ 8*(c&15)]
    u16* sB = (u16*)(smem + 32768);            // w1t [ci][m ^ 8*(ci&15)]
    int isf = detect_isf((const u16*)xr, tid, 256);
    int blk = bi;                              // tap*3 + br
    int tap = blk / 3, br = blk - tap * 3;
    const void* w1 = br == 0 ? w1q : (br == 1 ? w1k : w1v);
    const void* w2 = br == 0 ? w2q : (br == 1 ? w2k : w2v);
    if (isf) {
      const float* w2f = (const float*)w2;
      const float* w1f = (const float*)w1;
#pragma unroll 4
      for (int i = 0; i < 64; ++i) {
        int e = i * 256 + tid;
        int c = e >> 7, m = e & 127;
        sA[c * 128 + (m ^ ((c & 15) << 3))] = f2h(w2f[e * 9 + tap]);
        int ci = e & 127;
        sB[ci * 128 + ((e >> 7) ^ ((ci & 15) << 3))] = f2h(w1f[e]);
      }
    } else {
      const u16* w2u = (const u16*)w2;
      const u16* w1u = (const u16*)w1;
#pragma unroll 4
      for (int i = 0; i < 64; ++i) {
        int e = i * 256 + tid;
        int c = e >> 7, m = e & 127;
        sA[c * 128 + (m ^ ((c & 15) << 3))] = f2h(b2f(w2u[e * 9 + tap]));
        int ci = e & 127;
        sB[ci * 128 + ((e >> 7) ^ ((ci & 15) << 3))] = f2h(b2f(w1u[e]));
      }
    }
    __syncthreads();
    int lane = tid & 63, wv = tid >> 6;
    int m0w = (wv >> 1) * 64, n0w = (wv & 1) * 64;   // c-range, ci-range
    f32x4 acc[4][4] = {};
#pragma unroll
    for (int k0 = 0; k0 < 4; ++k0) {
      int mrow = k0 * 32 + (lane >> 4) * 8;
      int4 a4[4], b4[4];
#pragma unroll
      for (int mi = 0; mi < 4; ++mi) {
        int c = m0w + mi * 16 + (lane & 15);
        a4[mi] = *(const int4*)&sA[c * 128 + (mrow ^ ((c & 15) << 3))];
      }
#pragma unroll
      for (int ni = 0; ni < 4; ++ni) {
        int ci = n0w + ni * 16 + (lane & 15);
        b4[ni] = *(const int4*)&sB[ci * 128 + (mrow ^ ((ci & 15) << 3))];
      }
#pragma unroll
      for (int mi = 0; mi < 4; ++mi)
#pragma unroll
        for (int ni = 0; ni < 4; ++ni)
          acc[mi][ni] = mfma16(a4[mi], b4[ni], acc[mi][ni]);
    }
    __syncthreads();
#pragma unroll
    for (int mi = 0; mi < 4; ++mi)
#pragma unroll
      for (int ni = 0; ni < 4; ++ni) {
#pragma unroll
        for (int r = 0; r < 4; ++r) {
          int c = m0w + mi * 16 + (lane >> 4) * 4 + r;
          int ci = n0w + ni * 16 + (lane & 15);
          sA[c * 128 + ci] = f2h(acc[mi][ni][r]);    // LDS linear [c][ci]
        }
      }
    __syncthreads();
    int4* dst = (int4*)((char*)weff + (size_t)blk * 32768);
#pragma unroll
    for (int i = 0; i < 8; ++i) {
      int gidx = i * 256 + tid;
      int k0 = gidx >> 9;
      int ch = gidx & 511;
      int mt = ch >> 6, l = ch & 63;
      int c = mt * 16 + (l & 15);
      int g = k0 * 4 + (l >> 4);
      dst[gidx] = *(const int4*)((const char*)sA + c * 256 + g * 16);
    }
    return;
  }

  int li = bi - 27;                            // 0..259
  if (li >= 256) {                             // pad-row zeroing blocks
    int pid = li - 256;
    int b = pid >> 1, row = (pid & 1) ? 129 : 0;
    char* rbase = (char*)xnt + (size_t)(b * 130 + row) * XROW;
    int4 z = make_int4(0, 0, 0, 0);
    for (int i = 0; i < 9; ++i) {
      int idx = i * 256 + tid;
      if (idx < 2080) *(int4*)(rbase + idx * 16) = z;
    }
    return;
  }
  if (li == 0) {
    for (int i = tid; i < 4096; i += 256) attnb[i] = 0.f;
  }
  float* sx = (float*)smem;                    // 64KB raw f32 x, [c][chunk], phys = logical^(c&31)
  u16* sn = (u16*)(smem + 65536);              // 32KB f16 xn, [w][chunk g^(w&15)]
  float* sg = (float*)(smem + 98304);
  float* sb = (float*)(smem + 98816);
  int b = li >> 7, h = li & 127;
  int isf = detect_isf((const u16*)xr, tid, 256);
  if (tid < 128) {
    sg[tid] = isf ? ((const float*)gr)[tid] : b2f(((const u16*)gr)[tid]);
    sb[tid] = isf ? ((const float*)br_)[tid] : b2f(((const u16*)br_)[tid]);
  }
  if (isf) {
#pragma unroll
    for (int it = 0; it < 16; ++it) {
      int d = it * 4096 + tid * 16;
      int c = d >> 9;
      int p = (d >> 4) & 31;
      int sc = p ^ (c & 31);
      const char* src = (const char*)xr + (size_t)(b * 128 + c) * 65536 + (size_t)h * 512 + (sc << 4);
      gload16(src, (char*)sx + d);
    }
  } else {
    int c = tid >> 1, half = tid & 1;
    const u16* xu = (const u16*)xr + ((size_t)(b * 128 + c) * 128 + h) * 128 + half * 64;
    for (int i = 0; i < 16; ++i) {
      int phys = (half * 16 + i) ^ (c & 31);
      float* dst = sx + c * 128 + phys * 4;
#pragma unroll
      for (int j = 0; j < 4; ++j) dst[j] = b2f(xu[i * 4 + j]);
    }
  }
  __syncthreads();
  int c = tid >> 1, half = tid & 1;
  float sum = 0.f, sq = 0.f;
#pragma unroll
  for (int i = 0; i < 16; ++i) {
    int phys = (half * 16 + i) ^ (c & 31);
    const float* v = sx + c * 128 + phys * 4;
#pragma unroll
    for (int j = 0; j < 4; ++j) { float f = v[j]; sum += f; sq += f * f; }
  }
  sum += __shfl_xor(sum, 1);
  sq  += __shfl_xor(sq, 1);
  float mu = sum * 0.0078125f;
  float var = sq * 0.0078125f - mu * mu;
  float rs = rsqrtf(var + 1e-5f);
  int cg = c >> 3, cl = c & 7;
#pragma unroll
  for (int i = 0; i < 16; ++i) {
    int logical = half * 16 + i;
    int phys = logical ^ (c & 31);
    const float* v = sx + c * 128 + phys * 4;
#pragma unroll
    for (int j = 0; j < 4; ++j) {
      int w = logical * 4 + j;
      sn[w * 128 + (((cg ^ (w & 15)) << 3) | cl)] = f2h((v[j] - mu) * rs * sg[w] + sb[w]);
    }
  }
  __syncthreads();
  char* obase = (char*)xnt + (size_t)(b * 130 + h + 1) * XROW;
#pragma unroll
  for (int i = 0; i < 8; ++i) {
    int idx = i * 256 + tid;
    int g = idx >> 7, w = idx & 127;
    int phys = g ^ (w & 15);
    *(int4*)(obase + (g * 130 + w + 1) * 16) = *(const int4*)((const char*)sn + w * 256 + (phys << 4));
  }
  if (tid < 32) {
    int g = tid >> 1, side = tid & 1;
    *(int4*)(obase + (g * 130 + (side ? 129 : 0)) * 16) = make_int4(0, 0, 0, 0);
  }
}

// ---------------- K2: Q,K,V eff-3x3 conv, CO-HALF split (block = b,h,cohalf: co 64 x w 128).
// Each block stages only its co-half of every weight tile: 16KB/tile, 432KB/block (HALVED).
// 2x16KB dbuf (48KB LDS total). 27 steps x 32 MFMA, plain __syncthreads.
// bc from padded xnt, prefetched one tap ahead. Fused per-head Gram -> f32 atomics.
#define STAGE_T(T, BUF) do { \
    const char* base_ = (const char*)weff + (size_t)(T) * 32768 + (size_t)cohalf * 4096; \
    char* dst_ = wq + (BUF) * 16384; \
    _Pragma("unroll") \
    for (int i_ = 0; i_ < 4; ++i_) \
      gload16(base_ + i_ * 8192 + tid * 16, dst_ + i_ * 4096 + tid * 16); \
  } while (0)

#define BC_LOAD(DST, T6) do { \
    int dy_ = (T6) / 3, dx_ = (T6) % 3; \
    const char* rb_ = (const char*)xnt + (size_t)(b * 130 + h + dy_) * XROW; \
    _Pragma("unroll") \
    for (int kk = 0; kk < 4; ++kk) \
      _Pragma("unroll") \
      for (int ni = 0; ni < 2; ++ni) { \
        int wp1 = n0l + ni * 16 + (lane & 15) + dx_;   /* w+1, always 0..129 */ \
        int chunk = (kk * 4 + (lane >> 4)) * 130 + wp1; \
        DST[kk][ni] = *(const int4*)(rb_ + chunk * 16); \
      } \
  } while (0)

#define QFULL(ACC, QB) do { \
    _Pragma("unroll") \
    for (int k0 = 0; k0 < 4; ++k0) { \
      int4 af[4]; \
      _Pragma("unroll") \
      for (int mi = 0; mi < 4; ++mi) \
        af[mi] = *(const int4*)((QB) + k0 * 4096 + mi * 1024 + lane * 16); \
      _Pragma("unroll") \
      for (int mi = 0; mi < 4; ++mi) { \
        ACC[mi][0] = mfma16(af[mi], bcA[k0][0], ACC[mi][0]); \
        ACC[mi][1] = mfma16(af[mi], bcA[k0][1], ACC[mi][1]); \
      } \
    } \
  } while (0)

__global__ __launch_bounds__(256, 2) void k_conv(const u16* __restrict__ xnt,
    const u16* __restrict__ weff, u16* __restrict__ Vc, float* __restrict__ attnb) {
  __shared__ __align__(16) char wq[49152];      // 2x16KB dbuf; epilogue scrQ/K/V 48KB
  int tid = threadIdx.x, lane = tid & 63, wv = tid >> 6;
  int bi = blockIdx.x;
  int cohalf = bi & 1, h = (bi >> 1) & 127, b = bi >> 8;
  int n0l = wv * 32;                            // wave's w range (32 of 128)

  int4 bcA[4][2], bcB[4][2];
  BC_LOAD(bcA, 0);
  STAGE_T(0, 0);
  __syncthreads();

  f32x4 aq[4][2] = {}, ak[4][2] = {}, av[4][2] = {};

  for (int t = 0; t < 27; ++t) {                // t = tap*3 + br
    int br = t % 3, tgrp = t / 3;
    if (t + 1 < 27) STAGE_T(t + 1, (t + 1) & 1);     // prefetch next co-half tile
    if (br == 0) {
      if (tgrp > 0) {
#pragma unroll
        for (int kk = 0; kk < 4; ++kk)
#pragma unroll
          for (int ni = 0; ni < 2; ++ni) bcA[kk][ni] = bcB[kk][ni];
      }
      if (tgrp < 8) BC_LOAD(bcB, tgrp + 1);     // prefetch next tap's fragments (pure loads)
    }
    const char* qb = wq + (t & 1) * 16384;
    if (br == 0)      QFULL(aq, qb);
    else if (br == 1) QFULL(ak, qb);
    else              QFULL(av, qb);
    __syncthreads();                            // drains prefetch; protects buffer reuse
  }
  // ---- epilogue: Q,K,V (co64 x w128) -> LDS scratch [c][wl]; per-head Gram -> atomics; V out ----
  u16* scrQ = (u16*)wq;
  u16* scrK = (u16*)(wq + 16384);
  u16* scrV = (u16*)(wq + 32768);
#pragma unroll
  for (int mi = 0; mi < 4; ++mi)
#pragma unroll
    for (int ni = 0; ni < 2; ++ni)
#pragma unroll
      for (int r = 0; r < 4; ++r) {
        int cc = mi * 16 + (lane >> 4) * 4 + r;       // 0..63
        int wl = n0l + ni * 16 + (lane & 15);         // 0..127
        scrQ[cc * 128 + wl] = f2h(aq[mi][ni][r]);
        scrK[cc * 128 + wl] = f2h(ak[mi][ni][r]);
        scrV[cc * 128 + wl] = f2h(av[mi][ni][r]);
      }
  __syncthreads();
  {
    int hdg = cohalf * 4 + wv;                  // this wave's head
    f32x4 g = {};
#pragma unroll
    for (int k2 = 0; k2 < 4; ++k2) {            // contraction: 16 ci x 8 wg = 128 slots
      PK A, Bq;
#pragma unroll
      for (int jj = 0; jj < 8; ++jj) {
        int k = (lane >> 4) * 8 + jj;           // 0..31
        int ci = k2 * 4 + (k >> 3);
        int wg = k & 7;
        A.u[jj]  = scrK[(wv * 16 + ci) * 128 + wg * 16 + (lane & 15)];
        Bq.u[jj] = scrQ[(wv * 16 + ci) * 128 + wg * 16 + (lane & 15)];
      }
      g = mfma16(A.i, Bq.i, g);
    }
#pragma unroll
    for (int r = 0; r < 4; ++r)
      atomicAdd(&attnb[((b * 8 + hdg) * 16 + (lane >> 4) * 4 + r) * 16 + (lane & 15)], g[r]);
  }
  char* dstV = (char*)Vc + (size_t)(b * 128 + cohalf * 64) * 32768 + (size_t)h * 256;
#pragma unroll
  for (int i = 0; i < 4; ++i) {
    int gi = i * 256 + tid;                     // 0..1023
    int c = gi >> 4, off = (gi & 15) << 4;      // 64 rows x 256B
    *(int4*)(dstV + (size_t)c * 32768 + off) = *(const int4*)((const char*)scrV + c * 256 + off);
  }
}

// ---------------- K4: softmax + fold wo: W2[b][co][k=hd*16+dd] (f16, swizzled) --------------------
__global__ __launch_bounds__(256) void k_w2(const float* __restrict__ attnb,
    const void* __restrict__ wo, const void* __restrict__ scale,
    const u16* __restrict__ xdet, u16* __restrict__ w2s) {
  __shared__ float P[256];
  int b = blockIdx.x, hd = blockIdx.y;
  int tid = threadIdx.x;
  int isf = detect_isf(xdet, tid, 256);
  float sc = isf ? ((const float*)scale)[0] : b2f(((const u16*)scale)[0]);
  float inv_sc = 1.f / sc;
  P[tid] = attnb[(b * 8 + hd) * 256 + tid] * inv_sc;
  __syncthreads();
  if (tid < 16) {
    int dk = tid;
    float m = -1e30f;
#pragma unroll
    for (int j = 0; j < 16; ++j) m = fmaxf(m, P[dk * 16 + j]);
    float e[16]; float s = 0.f;
#pragma unroll
    for (int j = 0; j < 16; ++j) { e[j] = expf(P[dk * 16 + j] - m); s += e[j]; }
    float is = 1.f / s;
#pragma unroll
    for (int j = 0; j < 16; ++j) P[dk * 16 + j] = e[j] * is;
  }
  __syncthreads();
  int co = tid & 127, kg = tid >> 7;
  float wr[16];
  if (isf) {
    const float* wof = (const float*)wo;
#pragma unroll
    for (int d = 0; d < 16; ++d) wr[d] = wof[co * 128 + hd * 16 + d];
  } else {
    const u16* wou = (const u16*)wo;
#pragma unroll
    for (int d = 0; d < 16; ++d) wr[d] = b2f(wou[co * 128 + hd * 16 + d]);
  }
  PK p;
#pragma unroll
  for (int j = 0; j < 8; ++j) {
    int dd = kg * 8 + j;
    float a = 0.f;
#pragma unroll
    for (int d = 0; d < 16; ++d) a += wr[d] * P[dd * 16 + d];
    p.u[j] = f2h(a);
  }
  int slot = hd * 2 + kg;
  *(int4*)((char*)w2s + (size_t)b * 32768 + co * 256 + ((slot ^ (co & 7)) << 4)) = p.i;
}

// ---------------- K5: out = W2 @ Vbrick + x, w-split (b,h,whalf), 2 blocks/CU ---------------------
__global__ __launch_bounds__(256, 2) void k_final(const u16* __restrict__ w2s,
    const u16* __restrict__ Vc, const void* __restrict__ xr, void* __restrict__ outr) {
  __shared__ __align__(16) char sW[32768];
  __shared__ __align__(16) char sBk[16384];     // 64 brick rows x 256B
  int tid = threadIdx.x, lane = tid & 63, wv = tid >> 6;
  int bi = blockIdx.x;
  int whalf = bi & 1, h = (bi >> 1) & 127, b = bi >> 8;
  int isf = detect_isf((const u16*)xr, tid, 256);
  const char* wsrc = (const char*)w2s + (size_t)b * 32768;
#pragma unroll
  for (int i = 0; i < 8; ++i) {
    int off = i * 4096 + tid * 16;
    gload16(wsrc + off, sW + off);
  }
#pragma unroll
  for (int i = 0; i < 4; ++i) {                 // V brick: 64 gathered rows for this w-half
    int gi = i * 256 + tid;                     // 0..1023
    int lr = gi >> 4, chunk = gi & 15;
    int hd8 = lr >> 3, rl = whalf * 8 + (lr & 7);
    int cv = hd8 * 16 + (h >> 3);
    int hv = (h & 7) * 16 + rl;
    const char* src = (const char*)Vc + (size_t)(b * 128 + cv) * 32768 + (size_t)hv * 256 + (chunk << 4);
    gload16(src, sBk + gi * 16);
  }
  __syncthreads();
  int m0 = (wv >> 1) * 64, n0l = (wv & 1) * 32;
  f32x4 acc[4][2] = {};
#pragma unroll
  for (int k0i = 0; k0i < 4; ++k0i) {
    int4 af[4], bfr[2];
#pragma unroll
    for (int mi = 0; mi < 4; ++mi) {
      int cc = m0 + mi * 16 + (lane & 15);
      int slot = (k0i * 4 + (lane >> 4)) ^ (cc & 7);
      af[mi] = *(const int4*)(sW + cc * 256 + (slot << 4));
    }
#pragma unroll
    for (int ni = 0; ni < 2; ++ni) {
      int wl = n0l + ni * 16 + (lane & 15);
      int k = k0i * 32 + (lane >> 4) * 8;
      int hd8 = k >> 4, dd0 = k & 15;
      bfr[ni] = *(const int4*)(sBk + (hd8 * 8 + (wl >> 3)) * 256 + ((wl & 7) * 32 + dd0 * 2));
    }
#pragma unroll
    for (int mi = 0; mi < 4; ++mi)
#pragma unroll
      for (int ni = 0; ni < 2; ++ni)
        acc[mi][ni] = mfma16(af[mi], bfr[ni], acc[mi][ni]);
  }
  if (isf) {
    const float* xf = (const float*)xr;
    float* of = (float*)outr;
#pragma unroll
    for (int mi = 0; mi < 4; ++mi)
#pragma unroll
      for (int ni = 0; ni < 2; ++ni) {
        int w = whalf * 64 + n0l + ni * 16 + (lane & 15);
#pragma unroll
        for (int r = 0; r < 4; ++r) {
          int cc = m0 + mi * 16 + (lane >> 4) * 4 + r;
          size_t idx = ((size_t)(b * 128 + cc) * 128 + (size_t)h) * 128 + w;
          of[idx] = acc[mi][ni][r] + xf[idx];
        }
      }
  } else {
    const u16* xu = (const u16*)xr;
    u16* ou = (u16*)outr;
#pragma unroll
    for (int mi = 0; mi < 4; ++mi)
#pragma unroll
      for (int ni = 0; ni < 2; ++ni) {
        int w = whalf * 64 + n0l + ni * 16 + (lane & 15);
#pragma unroll
        for (int r = 0; r < 4; ++r) {
          int cc = m0 + mi * 16 + (lane >> 4) * 4 + r;
          size_t idx = ((size_t)(b * 128 + cc) * 128 + (size_t)h) * 128 + w;
          ou[idx] = f2b(acc[mi][ni][r] + b2f(xu[idx]));
        }
      }
  }
}

extern "C" void kernel_launch(void* const* d_in, const int* in_sizes, int n_in,
                              void* d_out, int out_size, void* d_ws, size_t ws_size,
                              hipStream_t stream) {
  (void)in_sizes; (void)n_in; (void)out_size; (void)ws_size;
  const void* x     = d_in[0];
  const void* gamma = d_in[1];
  const void* beta  = d_in[2];
  const void* scale = d_in[3];
  const void* w1q = d_in[4];
  const void* w2q = d_in[5];
  const void* w1k = d_in[6];
  const void* w2k = d_in[7];
  const void* w1v = d_in[8];
  const void* w2v = d_in[9];
  const void* wo  = d_in[10];
  char* ws = (char*)d_ws;
  u16* xnt     = (u16*)(ws);                           // 8.66 MB padded frag-major f16
  u16* weff    = (u16*)(ws + (9u << 20));              // 864 KB fused 3x3 weights f16, frag-major
  u16* Vc      = (u16*)(ws + (10u << 20));             // 8 MB [b][c][h][w] f16 linear
  float* attnb = (float*)(ws + (18u << 20));           // 16 KB f32 (zeroed by LN block)
  u16* w2s     = (u16*)(ws + (18u << 20) + 65536);     // 64 KB f16, swizzled

  hipLaunchKernelGGL(k_lnweff, dim3(287), dim3(256), 0, stream,
                     x, gamma, beta, w1q, w2q, w1k, w2k, w1v, w2v, weff, xnt, attnb);
  hipLaunchKernelGGL(k_conv, dim3(512), dim3(256), 0, stream, xnt, weff, Vc, attnb);
  hipLaunchKernelGGL(k_w2, dim3(2, 8), dim3(256), 0, stream, attnb, wo, scale, (const u16*)x, w2s);
  hipLaunchKernelGGL(k_final, dim3(512), dim3(256), 0, stream, w2s, Vc, x, d_out);
}